// Round 12
// baseline (177.972 us; speedup 1.0000x reference)
//
#include <hip/hip_runtime.h>

#define NS 32768
#define NC 395
#define FD 512
#define SPL 32
#define CHUNK (NS / SPL)   // 1024 samples per chunk: 2+2 MB -> fits 4 MiB XCD L2
#define TPB 256
#define NEL (NC * FD)

// Static device scratch — every slot rewritten each call.
// g_partial[(s*2+mod)][class][512]   (~51.8 MB)
__device__ float g_partial[SPL * 2 * NC * FD];
__device__ int   g_pcount[SPL * NC];

// ---------------------------------------------------------------------------
__device__ __forceinline__ void f4add(float4& a, const float4 b) {
    a.x += b.x; a.y += b.y; a.z += b.z; a.w += b.w;
}

// K1: one block per (class, chunk). XCD-swizzled decode: all 395 class-blocks
// of a chunk land on ONE XCD (blockIdx%8 round-robin) and are dispatch-
// adjacent, so the chunk's 4 MB working set is fetched once and re-served
// 395x from that XCD's private L2 instead of L3/fabric. Scan: 1 int4 load
// per thread (1024 targets). Gather: 2 waves per modality jointly cover the
// full 2 KB row; ~2.6 matching rows per block on average.
__global__ __launch_bounds__(TPB)
void gather_sum_kernel(const float4* __restrict__ m1,
                       const float4* __restrict__ m2,
                       const int* __restrict__ targets,
                       float* __restrict__ out) {
    int xcd  = blockIdx.x & 7;
    int idx  = blockIdx.x >> 3;       // 0 .. NC*4-1
    int sgrp = idx / NC;              // 0..3
    int c    = idx - sgrp * NC;       // class
    int s    = xcd + (sgrp << 3);     // chunk id 0..31 (same-chunk -> same XCD)
    int tid  = threadIdx.x;

    if (blockIdx.x == 0 && tid == 0) out[0] = 0.0f;  // zero before loss kernel

    __shared__ unsigned short sidx[CHUNK];  // chunk-local match list (2 KB)
    __shared__ int scnt;

    // ---- scan phase: one int4 load per thread covers all 1024 targets ----
    int sbase = s * CHUNK;
    const int4* t4 = reinterpret_cast<const int4*>(targets + sbase);
    int4 ta = t4[tid];
    if (tid == 0) scnt = 0;
    __syncthreads();
    int i0 = 4 * tid;   // chunk-local
    if (ta.x == c) sidx[atomicAdd(&scnt, 1)] = (unsigned short)i0;
    if (ta.y == c) sidx[atomicAdd(&scnt, 1)] = (unsigned short)(i0 + 1);
    if (ta.z == c) sidx[atomicAdd(&scnt, 1)] = (unsigned short)(i0 + 2);
    if (ta.w == c) sidx[atomicAdd(&scnt, 1)] = (unsigned short)(i0 + 3);
    __syncthreads();
    int cnt = scnt;

    // ---- gather phase: 128 threads/modality cover the full 512-dim row ----
    int mod = tid >> 7;               // modality (wave-pair uniform)
    int q   = tid & 127;              // float4 quad within the row
    const float4* src = (mod ? m2 : m1) + (size_t)sbase * 128;

    float4 a0 = make_float4(0.f, 0.f, 0.f, 0.f);
    float4 a1 = a0;

    int j = 0;
    for (; j + 2 <= cnt; j += 2) {
        float4 v0 = src[(size_t)sidx[j]     * 128 + q];
        float4 v1 = src[(size_t)sidx[j + 1] * 128 + q];
        f4add(a0, v0); f4add(a1, v1);
    }
    if (j < cnt)
        f4add(a0, src[(size_t)sidx[j] * 128 + q]);
    f4add(a0, a1);

    // partial[(s*2+mod)][c][q*4..] — always written (zeros if no matches).
    float4* dst = reinterpret_cast<float4*>(g_partial);
    dst[(((size_t)s * 2 + mod) * NC + c) * 128 + q] = a0;
    if (tid == 0) g_pcount[s * NC + c] = cnt;
}

// ---------------------------------------------------------------------------
__device__ __forceinline__ float smooth_l1(float d) {
    d = fabsf(d);
    return d < 1.0f ? 0.5f * d * d : d - 0.5f;
}

// K2: combine 64 partial slabs + counts, SmoothL1 weighted by count, reduce.
__global__ void loss_kernel(const float* __restrict__ centers,
                            float* __restrict__ out) {
    __shared__ float scnt[NC];
    int t = threadIdx.x;   // 256
    for (int c = t; c < NC; c += 256) {
        int sc = 0;
        for (int k = 0; k < SPL; k++) sc += g_pcount[k * NC + c];
        scnt[c] = (float)sc;
    }
    __syncthreads();

    float val = 0.0f;
    for (int gid = blockIdx.x * 256 + t; gid < NEL; gid += gridDim.x * 256) {
        int c = gid >> 9;          // FD == 512
        float cnt = scnt[c];
        if (cnt > 0.0f) {
            float s1 = 0.0f, s2 = 0.0f;
            #pragma unroll 8
            for (int k = 0; k < SPL; k++) {
                s1 += g_partial[(size_t)(2 * k)     * NEL + gid];
                s2 += g_partial[(size_t)(2 * k + 1) * NEL + gid];
            }
            float ctr = centers[gid];
            float inv = 1.0f / cnt;
            val += cnt * (smooth_l1(s1 * inv - ctr) + smooth_l1(s2 * inv - ctr));
        }
    }

    for (int off = 32; off > 0; off >>= 1)
        val += __shfl_down(val, off, 64);
    __shared__ float wsum[4];
    int lane = t & 63, wid = t >> 6;
    if (lane == 0) wsum[wid] = val;
    __syncthreads();
    if (t == 0) {
        float sm = wsum[0] + wsum[1] + wsum[2] + wsum[3];
        atomicAdd(out, sm * 5.9604644775390625e-08f);  // 1/(N*D) = 2^-24
    }
}

extern "C" void kernel_launch(void* const* d_in, const int* in_sizes, int n_in,
                              void* d_out, int out_size, void* d_ws, size_t ws_size,
                              hipStream_t stream) {
    const float4* m1 = (const float4*)d_in[0];
    const float4* m2 = (const float4*)d_in[1];
    const float* centers = (const float*)d_in[2];
    const int* targets = (const int*)d_in[3];
    float* out = (float*)d_out;

    gather_sum_kernel<<<NC * SPL, TPB, 0, stream>>>(m1, m2, targets, out);
    loss_kernel<<<512, 256, 0, stream>>>(centers, out);
}